// Round 6
// baseline (34431.110 us; speedup 1.0000x reference)
//
#include <hip/hip_runtime.h>

#define LSEQ 2048
#define CDIM 1024
#define NWG  64
#define NTHR 512

typedef _Float16 f16x8 __attribute__((ext_vector_type(8)));
typedef float    f32x4 __attribute__((ext_vector_type(4)));
typedef unsigned long long u64;
typedef unsigned int u32;

// Tag-exchange buffer: [parity][batch 8][512 packets]; packet = (tag:32 | f16 h[2j],h[2j+1]).
// Static device global (zero-init): no d_ws dependency, no OOB risk.
// Graph-replay safe: t=0 publish fully rewrites parity 0; stale parity-1 tags
// (2047 from a previous replay) cannot alias any expected tag before overwrite.
__device__ u64 g_hbuf[2 * 8 * 512];

static __device__ __forceinline__ f16x8 cvt8(const float4 lo, const float4 hh) {
  f16x8 r;
  r[0]=(_Float16)lo.x; r[1]=(_Float16)lo.y; r[2]=(_Float16)lo.z; r[3]=(_Float16)lo.w;
  r[4]=(_Float16)hh.x; r[5]=(_Float16)hh.y; r[6]=(_Float16)hh.z; r[7]=(_Float16)hh.w;
  return r;
}
static __device__ __forceinline__ f16x8 zero8() {
  f16x8 r;
#pragma unroll
  for (int i=0;i<8;++i) r[i]=(_Float16)0.f;
  return r;
}
static __device__ __forceinline__ float sigm(float v){ return 1.0f/(1.0f + __expf(-v)); }
static __device__ __forceinline__ float tanh_(float v){ return 2.0f*sigm(2.0f*v) - 1.0f; }
static __device__ __forceinline__ u32 pack_f16x2(float a, float b) {
  unsigned short ua = __builtin_bit_cast(unsigned short, (_Float16)a);
  unsigned short ub = __builtin_bit_cast(unsigned short, (_Float16)b);
  return (u32)ua | ((u32)ub << 16);
}

// Persistent LSTM. 64 WGs x 512 thr (8 waves); WG wg owns channels [wg*16, wg*16+16).
// wid even = x-waves (W_ih MFMA + gate combine + publish), nt = wid>>1.
// wid odd  = h-waves (gather h(t) + W_hh MFMA), nt = wid>>1.
// Lane map (l = tid&63): r = l&15 -> weight-row index (gate=r>>2, jq=r&3) on the
// MFMA N side and batch index on the M side; hi4 = l>>4 -> K-chunk / D-row group.
__global__ __launch_bounds__(NTHR, 2) void lstm_persistent(
    const float* __restrict__ x, const float* __restrict__ Wih,
    const float* __restrict__ Whh, const float* __restrict__ bih,
    const float* __restrict__ bhh, float* __restrict__ out)
{
  const int wg  = blockIdx.x;
  const int tid = threadIdx.x;
  const int wid = tid >> 6;
  const int l   = tid & 63;
  const int nt  = wid >> 1;          // 0..3
  const bool xw = (wid & 1) == 0;
  const int j0  = wg * 16;
  const int r   = l & 15;
  const int hi4 = l >> 4;            // 0..3
  const int gate= r >> 2;
  const int jq  = r & 3;
  const int row = gate*CDIM + j0 + nt*4 + jq;

  __shared__ _Float16 hstage[8][1032];   // +8 f16 pad: 16B-aligned rows, fewer bank conflicts
  __shared__ f32x4 partial[4][64];

  // ---- resident weight fragments (MFMA B operand), fp32 -> fp16 once ----
  f16x8 wf[32];
  {
    const float* W = xw ? Wih : Whh;
    const float* wr = W + (long)row*CDIM + hi4*8;
#pragma unroll
    for (int kk=0; kk<32; ++kk) {
      float4 lo = *(const float4*)(wr + kk*32);
      float4 hh = *(const float4*)(wr + kk*32 + 4);
      wf[kk] = cvt8(lo, hh);
    }
  }
  float bias = 0.f;
  if (xw) bias = bih[row] + bhh[row];
  float cst[4] = {0.f,0.f,0.f,0.f};      // cell state: lane holds (channel jq, batch hi4*4+rr)

  // ---- initial publish: tag 0, h=0, parity 0 (covers this WG's 8 packet cols x 8 batches) ----
  if (xw && gate==0 && (jq&1)==0 && hi4 < 2) {
    const int jp = wg*8 + nt*2 + (jq>>1);
    const int b0 = hi4*4;
#pragma unroll
    for (int rr=0; rr<4; ++rr)
      __hip_atomic_store(&g_hbuf[(long)(b0+rr)*512 + jp], (u64)0,
                         __ATOMIC_RELAXED, __HIP_MEMORY_SCOPE_AGENT);
  }

  for (int t=0; t<LSEQ; ++t) {
    const int par = t & 1;
    f32x4 accx = {0.f,0.f,0.f,0.f};
    if (xw) {
      // x-projection MFMAs (independent of h: overlaps publish->poll latency)
      f32x4 acc = {bias,bias,bias,bias};
      const int b = r;
      const float* xb = x + ((long)b*LSEQ + t)*CDIM + hi4*8;
#pragma unroll
      for (int kk=0; kk<32; ++kk) {
        f16x8 xf;
        if (b < 8) {
          float4 lo = *(const float4*)(xb + kk*32);
          float4 hh = *(const float4*)(xb + kk*32 + 4);
          xf = cvt8(lo, hh);
        } else xf = zero8();
        acc = __builtin_amdgcn_mfma_f32_16x16x32_f16(xf, wf[kk], acc, 0,0,0);
      }
      accx = acc;
    } else {
      // gather h(t): odd wave nt covers batches b = nt*2 + (l>>5); 16 packets/lane
      const int b  = nt*2 + (l >> 5);
      const int sl = l & 31;
      u64* src = g_hbuf + ((long)par*8 + b)*512;
      u64 v[16];
#pragma unroll
      for (int i=0;i<16;++i)
        v[i] = __hip_atomic_load(&src[i*32 + sl], __ATOMIC_RELAXED, __HIP_MEMORY_SCOPE_AGENT);
      const int cap = (t==0) ? (1<<17) : 1024;   // bounded spin: no watchdog kill if sync breaks
      for (int spin=0; spin<cap; ++spin) {
        int bad = 0;
#pragma unroll
        for (int i=0;i<16;++i) {
          if ((u32)(v[i]>>32) != (u32)t) {
            bad = 1;
            v[i] = __hip_atomic_load(&src[i*32 + sl], __ATOMIC_RELAXED, __HIP_MEMORY_SCOPE_AGENT);
          }
        }
        if (!__any(bad)) break;   // exit only after a clean full pass
      }
#pragma unroll
      for (int i=0;i<16;++i)
        *(u32*)&hstage[b][(i*32 + sl)*2] = (u32)v[i];
    }
    __syncthreads();               // hstage(t) ready
    if (!xw) {
      f32x4 acc = {0.f,0.f,0.f,0.f};
      const int b = r;
#pragma unroll
      for (int kk=0; kk<32; ++kk) {
        f16x8 hf;
        if (b < 8) hf = *(const f16x8*)&hstage[b][kk*32 + hi4*8];
        else hf = zero8();
        acc = __builtin_amdgcn_mfma_f32_16x16x32_f16(hf, wf[kk], acc, 0,0,0);
      }
      partial[nt][l] = acc;
    }
    __syncthreads();               // partials ready
    if (xw) {
      f32x4 p = partial[nt][l];
      float hres[4], hnb[4];
#pragma unroll
      for (int rr=0; rr<4; ++rr) {
        float v  = accx[rr] + p[rr];
        float v4 = __shfl_xor(v, 4);    // gate bit0 flip
        float v8 = __shfl_xor(v, 8);    // gate bit1 flip
        float v12= __shfl_xor(v4, 8);   // both
        float gi, gf, gg, go;
        {
          int k;
          k = gate;    gi = (k&2) ? ((k&1)?v12:v8) : ((k&1)?v4:v);
          k = gate^1;  gf = (k&2) ? ((k&1)?v12:v8) : ((k&1)?v4:v);
          k = gate^2;  gg = (k&2) ? ((k&1)?v12:v8) : ((k&1)?v4:v);
          k = gate^3;  go = (k&2) ? ((k&1)?v12:v8) : ((k&1)?v4:v);
        }
        float si = sigm(gi), sf = sigm(gf), sg = tanh_(gg), so = sigm(go);
        cst[rr] = sf*cst[rr] + si*sg;
        hres[rr]= so * tanh_(cst[rr]);
      }
#pragma unroll
      for (int rr=0; rr<4; ++rr) hnb[rr] = __shfl_xor(hres[rr], 1);  // channel j+1
      if (gate==0 && (jq&1)==0 && hi4 < 2) {
        const int j  = j0 + nt*4 + jq;       // even channel
        const int jp = j >> 1;
        const int b0 = hi4*4;
        const long p2 = (long)((t+1)&1);
        const u64 tag = ((u64)(u32)(t+1)) << 32;
#pragma unroll
        for (int rr=0; rr<4; ++rr) {
          u32 d = pack_f16x2(hres[rr], hnb[rr]);
          __hip_atomic_store(&g_hbuf[(p2*8 + b0+rr)*512 + jp], tag | (u64)d,
                             __ATOMIC_RELAXED, __HIP_MEMORY_SCOPE_AGENT);
          float2 o2; o2.x = hres[rr]; o2.y = hnb[rr];
          *(float2*)(out + ((long)(b0+rr)*LSEQ + t)*CDIM + j) = o2;
        }
      }
    }
  }
}

extern "C" void kernel_launch(void* const* d_in, const int* in_sizes, int n_in,
                              void* d_out, int out_size, void* d_ws, size_t ws_size,
                              hipStream_t stream) {
  const float* x   = (const float*)d_in[0];
  const float* Wih = (const float*)d_in[1];
  const float* Whh = (const float*)d_in[2];
  const float* bih = (const float*)d_in[3];
  const float* bhh = (const float*)d_in[4];
  float* outp = (float*)d_out;
  (void)in_sizes; (void)n_in; (void)out_size; (void)d_ws; (void)ws_size;
  hipLaunchKernelGGL(lstm_persistent, dim3(NWG), dim3(NTHR), 0, stream,
                     x, Wih, Whh, bih, bhh, outp);
}

// Round 9
// 33069.565 us; speedup vs baseline: 1.0412x; 1.0412x over previous
//
#include <hip/hip_runtime.h>

#define LSEQ 2048
#define CDIM 1024
#define NWG  64
#define NTHR 512

typedef _Float16 f16x8 __attribute__((ext_vector_type(8)));
typedef float    f32x4 __attribute__((ext_vector_type(4)));
typedef unsigned long long u64;
typedef unsigned int u32;

// Tag-exchange buffer: [parity][batch 8][512 packets]; packet = (tag:32 | f16 h[2j],h[2j+1]).
// Static device global (zero-init): no d_ws dependency, no OOB risk.
// Graph-replay safe: t=0 publish fully rewrites parity 0; stale parity-1 tags
// cannot alias any expected tag before overwrite (exact tag match everywhere).
__device__ u64 g_hbuf[2 * 8 * 512];

static __device__ __forceinline__ f16x8 cvt8(const float4 lo, const float4 hh) {
  f16x8 r;
  r[0]=(_Float16)lo.x; r[1]=(_Float16)lo.y; r[2]=(_Float16)lo.z; r[3]=(_Float16)lo.w;
  r[4]=(_Float16)hh.x; r[5]=(_Float16)hh.y; r[6]=(_Float16)hh.z; r[7]=(_Float16)hh.w;
  return r;
}
static __device__ __forceinline__ f16x8 zero8() {
  f16x8 r;
#pragma unroll
  for (int i=0;i<8;++i) r[i]=(_Float16)0.f;
  return r;
}
static __device__ __forceinline__ float sigm(float v){ return 1.0f/(1.0f + __expf(-v)); }
static __device__ __forceinline__ float tanh_(float v){ return 2.0f*sigm(2.0f*v) - 1.0f; }
static __device__ __forceinline__ u32 pack_f16x2(float a, float b) {
  unsigned short ua = __builtin_bit_cast(unsigned short, (_Float16)a);
  unsigned short ub = __builtin_bit_cast(unsigned short, (_Float16)b);
  return (u32)ua | ((u32)ub << 16);
}

// Persistent LSTM. 64 WGs x 512 thr (8 waves); WG wg owns channels [wg*16, wg*16+16).
// wid even = x-waves (W_ih MFMA + gate combine + publish), nt = wid>>1.
// wid odd  = h-waves (gather h(t) + W_hh MFMA), nt = wid>>1.
// Detect path: wid 1 polls 64 canary packets (8B x 64 lanes per pass,
// vs 2 MB/pass full-data polling) -> LDS flag -> single bulk tag-verified pass.
__global__ __launch_bounds__(NTHR, 2) void lstm_persistent(
    const float* __restrict__ x, const float* __restrict__ Wih,
    const float* __restrict__ Whh, const float* __restrict__ bih,
    const float* __restrict__ bhh, float* __restrict__ out)
{
  const int wg  = blockIdx.x;
  const int tid = threadIdx.x;
  const int wid = tid >> 6;
  const int l   = tid & 63;
  const int nt  = wid >> 1;          // 0..3
  const bool xw = (wid & 1) == 0;
  const int j0  = wg * 16;
  const int r   = l & 15;
  const int hi4 = l >> 4;            // 0..3
  const int gate= r >> 2;
  const int jq  = r & 3;
  const int row = gate*CDIM + j0 + nt*4 + jq;

  __shared__ _Float16 hstage[8][1032];   // +8 f16 pad: 16B-aligned rows, fewer bank conflicts
  __shared__ f32x4 partial[4][64];
  __shared__ int ready_flag;             // monotone t+1, set by wid1 after canary detect

  // ---- resident weight fragments (MFMA B operand), fp32 -> fp16 once ----
  f16x8 wf[32];
  {
    const float* W = xw ? Wih : Whh;
    const float* wr = W + (long)row*CDIM + hi4*8;
#pragma unroll
    for (int kk=0; kk<32; ++kk) {
      float4 lo = *(const float4*)(wr + kk*32);
      float4 hh = *(const float4*)(wr + kk*32 + 4);
      wf[kk] = cvt8(lo, hh);
    }
  }
  float bias = 0.f;
  if (xw) bias = bih[row] + bhh[row];
  float cst[4] = {0.f,0.f,0.f,0.f};      // cell state: lane holds (channel jq, batch hi4*4+rr)

  if (tid == 0) ready_flag = 0;

  // ---- initial publish: tag 0, h=0, parity 0 (covers this WG's 8 packet cols x 8 batches) ----
  if (xw && gate==0 && (jq&1)==0 && hi4 < 2) {
    const int jp = wg*8 + nt*2 + (jq>>1);
    const int b0 = hi4*4;
#pragma unroll
    for (int rr=0; rr<4; ++rr)
      __hip_atomic_store(&g_hbuf[(long)(b0+rr)*512 + jp], (u64)0,
                         __ATOMIC_RELAXED, __HIP_MEMORY_SCOPE_AGENT);
  }
  __syncthreads();                       // ready_flag init visible before t-loop

  for (int t=0; t<LSEQ; ++t) {
    const int par = t & 1;
    f32x4 accx = {0.f,0.f,0.f,0.f};
    if (xw) {
      // x-projection MFMAs (independent of h: overlaps publish->poll latency)
      f32x4 acc = {bias,bias,bias,bias};
      const int b = r;
      const float* xb = x + ((long)b*LSEQ + t)*CDIM + hi4*8;
#pragma unroll
      for (int kk=0; kk<32; ++kk) {
        f16x8 xf;
        if (b < 8) {
          float4 lo = *(const float4*)(xb + kk*32);
          float4 hh = *(const float4*)(xb + kk*32 + 4);
          xf = cvt8(lo, hh);
        } else xf = zero8();
        acc = __builtin_amdgcn_mfma_f32_16x16x32_f16(xf, wf[kk], acc, 0,0,0);
      }
      accx = acc;
    } else {
      // ---- detect h(t): canary poll (wid1) + LDS flag (wid 3,5,7) ----
      if (wid == 1) {
        const u64* can = g_hbuf + (long)par*4096 + (long)l*8;  // producer l's canary (b=0, jp=l*8)
        const int ccap = (t==0) ? (1<<20) : (1<<16);
        for (int spin=0; spin<ccap; ++spin) {
          u64 cv = __hip_atomic_load(can, __ATOMIC_RELAXED, __HIP_MEMORY_SCOPE_AGENT);
          if (__all((u32)(cv>>32) == (u32)t)) break;
        }
        if (l == 0)
          __hip_atomic_store(&ready_flag, t+1, __ATOMIC_RELAXED, __HIP_MEMORY_SCOPE_WORKGROUP);
      } else {
        for (int spin=0; spin<(1<<20); ++spin) {
          if (__hip_atomic_load(&ready_flag, __ATOMIC_RELAXED, __HIP_MEMORY_SCOPE_WORKGROUP) >= t+1)
            break;
        }
      }
      // ---- bulk gather: odd wave nt covers batches b = nt*2 + (l>>5); 16 packets/lane ----
      const int b  = nt*2 + (l >> 5);
      const int sl = l & 31;
      u64* src = g_hbuf + ((long)par*8 + b)*512;
      u64 v[16];
#pragma unroll
      for (int i=0;i<16;++i)
        v[i] = __hip_atomic_load(&src[i*32 + sl], __ATOMIC_RELAXED, __HIP_MEMORY_SCOPE_AGENT);
      for (int spin=0; spin<1024; ++spin) {       // tag verify: exact-match re-poll (rare)
        int bad = 0;
#pragma unroll
        for (int i=0;i<16;++i) {
          if ((u32)(v[i]>>32) != (u32)t) {
            bad = 1;
            v[i] = __hip_atomic_load(&src[i*32 + sl], __ATOMIC_RELAXED, __HIP_MEMORY_SCOPE_AGENT);
          }
        }
        if (!__any(bad)) break;
      }
#pragma unroll
      for (int i=0;i<16;++i)
        *(u32*)&hstage[b][(i*32 + sl)*2] = (u32)v[i];
    }
    __syncthreads();               // hstage(t) ready
    if (!xw) {
      f32x4 acc = {0.f,0.f,0.f,0.f};
      const int b = r;
#pragma unroll
      for (int kk=0; kk<32; ++kk) {
        f16x8 hf;
        if (b < 8) hf = *(const f16x8*)&hstage[b][kk*32 + hi4*8];
        else hf = zero8();
        acc = __builtin_amdgcn_mfma_f32_16x16x32_f16(hf, wf[kk], acc, 0,0,0);
      }
      partial[nt][l] = acc;
    }
    __syncthreads();               // partials ready
    if (xw) {
      f32x4 p = partial[nt][l];
      float hres[4], hnb[4];
#pragma unroll
      for (int rr=0; rr<4; ++rr) {
        float v  = accx[rr] + p[rr];
        float v4 = __shfl_xor(v, 4);    // gate bit0 flip
        float v8 = __shfl_xor(v, 8);    // gate bit1 flip
        float v12= __shfl_xor(v4, 8);   // both
        float gi, gf, gg, go;
        {
          int k;
          k = gate;    gi = (k&2) ? ((k&1)?v12:v8) : ((k&1)?v4:v);
          k = gate^1;  gf = (k&2) ? ((k&1)?v12:v8) : ((k&1)?v4:v);
          k = gate^2;  gg = (k&2) ? ((k&1)?v12:v8) : ((k&1)?v4:v);
          k = gate^3;  go = (k&2) ? ((k&1)?v12:v8) : ((k&1)?v4:v);
        }
        float si = sigm(gi), sf = sigm(gf), sg = tanh_(gg), so = sigm(go);
        cst[rr] = sf*cst[rr] + si*sg;
        hres[rr]= so * tanh_(cst[rr]);
      }
#pragma unroll
      for (int rr=0; rr<4; ++rr) hnb[rr] = __shfl_xor(hres[rr], 1);  // channel j+1
      if (gate==0 && (jq&1)==0 && hi4 < 2) {
        const int j  = j0 + nt*4 + jq;       // even channel
        const int jp = j >> 1;
        const int b0 = hi4*4;
        const long p2 = (long)((t+1)&1);
        const u64 tag = ((u64)(u32)(t+1)) << 32;
#pragma unroll
        for (int rr=0; rr<4; ++rr) {
          u32 d = pack_f16x2(hres[rr], hnb[rr]);
          __hip_atomic_store(&g_hbuf[(p2*8 + b0+rr)*512 + jp], tag | (u64)d,
                             __ATOMIC_RELAXED, __HIP_MEMORY_SCOPE_AGENT);
          float2 o2; o2.x = hres[rr]; o2.y = hnb[rr];
          *(float2*)(out + ((long)(b0+rr)*LSEQ + t)*CDIM + j) = o2;
        }
      }
    }
  }
}

extern "C" void kernel_launch(void* const* d_in, const int* in_sizes, int n_in,
                              void* d_out, int out_size, void* d_ws, size_t ws_size,
                              hipStream_t stream) {
  const float* x   = (const float*)d_in[0];
  const float* Wih = (const float*)d_in[1];
  const float* Whh = (const float*)d_in[2];
  const float* bih = (const float*)d_in[3];
  const float* bhh = (const float*)d_in[4];
  float* outp = (float*)d_out;
  (void)in_sizes; (void)n_in; (void)out_size; (void)d_ws; (void)ws_size;
  hipLaunchKernelGGL(lstm_persistent, dim3(NWG), dim3(NTHR), 0, stream,
                     x, Wih, Whh, bih, bhh, outp);
}